// Round 1
// 532.887 us; speedup vs baseline: 1.0143x; 1.0143x over previous
//
#include <hip/hip_runtime.h>

// BSplineEncoder: out[n, c] = b[c] + sum_{k=0..3} N_k(x_n) * W[c, span(x_n)-3+k]
// Cubic clamped B-spline, knots [0,0,0,0, 1/7..6/7, 1,1,1,1], 10 basis funcs.
// Write-bound: 537 MB output stream. 8 threads per x (16 cols each via 4x float4).
//
// R1 changes vs baseline:
//  - sW padded to [NB][NC+4]: row stride 132 words == 4 (mod 32 banks).
//    Unpadded 128-word stride aliased all spline spans onto the same banks ->
//    ~5-way bank conflict on every sW ds_read_b128 (8 x-groups, random spans).
//    Rows within one read differ by <= 6 < 8, so padded layout is conflict-free.
//  - bias hoisted to registers (removes 4 broadcast LDS reads per wave-iter).
//  - non-temporal stores for the 537 MB output stream (don't churn L2; x stays hot).

constexpr int NC  = 128;   // output channels
constexpr int NB  = 10;    // basis functions
constexpr int PAD = 4;     // +4 floats: bank offset = 4*row (mod 32)

typedef float f32x4 __attribute__((ext_vector_type(4)));

__global__ __launch_bounds__(256, 8)
void bspline_enc_kernel(const float* __restrict__ xin,
                        const float* __restrict__ W,
                        const float* __restrict__ bias,
                        float* __restrict__ out,
                        int n)
{
    __shared__ float sW[NB][NC + PAD];   // transposed: sW[k][c] = W[c*NB + k]

    for (int i = threadIdx.x; i < NB * NC; i += 256) {
        int c = i / NB, k = i - c * NB;
        sW[k][c] = W[i];
    }
    __syncthreads();

    const int lane8 = threadIdx.x & 7;   // 16-col slice within the row
    const int xslot = threadIdx.x >> 3;  // which of 32 x's this block-iter
    const float k7 = 1.0f / 7.0f;

    // Bias for this thread's 16 fixed columns — loop-invariant, keep in VGPRs.
    f32x4 bias_r[4];
    #pragma unroll
    for (int q = 0; q < 4; ++q)
        bias_r[q] = *(const f32x4*)&bias[32 * q + 4 * lane8];

    for (long long base = (long long)blockIdx.x * 32; base < n;
         base += (long long)gridDim.x * 32) {
        long long xi = base + xslot;
        if (xi >= n) continue;           // n % 32 == 0 in practice

        float xv = xin[xi];
        xv = fminf(fmaxf(xv, 1e-9f), 1.0f);   // jnp.clip(x, 1e-9, 1.0)

        int s = (int)(xv * 7.0f);
        if (s > 6) s = 6;                // span j = s+3; nonzero basis s..s+3
        float fs = (float)s;

        // local knots around span (clamped ends via min/max)
        float tj   = fs * k7;
        float tjm1 = fmaxf(fs - 1.0f, 0.0f) * k7;
        float tjm2 = fmaxf(fs - 2.0f, 0.0f) * k7;
        float tjp1 = fminf((fs + 1.0f) * k7, 1.0f);
        float tjp2 = fminf((fs + 2.0f) * k7, 1.0f);
        float tjp3 = fminf((fs + 3.0f) * k7, 1.0f);

        float l1 = xv - tj,   r1 = tjp1 - xv;
        float l2 = xv - tjm1, r2 = tjp2 - xv;
        float l3 = xv - tjm2, r3 = tjp3 - xv;

        // De Boor local basis (degree 3): N0..N3 = B_{s..s+3,3}(x)
        float N0, N1, N2, N3;
        {   // d=1
            float t0 = 1.0f / (r1 + l1);
            N0 = r1 * t0;
            N1 = l1 * t0;
        }
        {   // d=2
            float t0 = N0 / (r1 + l2);
            float t1 = N1 / (r2 + l1);
            N0 = r1 * t0;
            N1 = l2 * t0 + r2 * t1;
            N2 = l1 * t1;
        }
        {   // d=3
            float t0 = N0 / (r1 + l3);
            float t1 = N1 / (r2 + l2);
            float t2 = N2 / (r3 + l1);
            N0 = r1 * t0;
            N1 = l3 * t0 + r2 * t1;
            N2 = l2 * t1 + r3 * t2;
            N3 = l1 * t2;
        }

        float* orow = out + xi * (long long)NC;
        #pragma unroll
        for (int q = 0; q < 4; ++q) {
            int c0 = 32 * q + 4 * lane8;  // each 8-lane group covers 32 contiguous cols
            f32x4 wa = *(const f32x4*)&sW[s + 0][c0];
            f32x4 wb = *(const f32x4*)&sW[s + 1][c0];
            f32x4 wc = *(const f32x4*)&sW[s + 2][c0];
            f32x4 wd = *(const f32x4*)&sW[s + 3][c0];
            f32x4 bb = bias_r[q];
            f32x4 acc;
            acc.x = bb.x + N0 * wa.x + N1 * wb.x + N2 * wc.x + N3 * wd.x;
            acc.y = bb.y + N0 * wa.y + N1 * wb.y + N2 * wc.y + N3 * wd.y;
            acc.z = bb.z + N0 * wa.z + N1 * wb.z + N2 * wc.z + N3 * wd.z;
            acc.w = bb.w + N0 * wa.w + N1 * wb.w + N2 * wc.w + N3 * wd.w;
            __builtin_nontemporal_store(acc, (f32x4*)&orow[c0]);
        }
    }
}

extern "C" void kernel_launch(void* const* d_in, const int* in_sizes, int n_in,
                              void* d_out, int out_size, void* d_ws, size_t ws_size,
                              hipStream_t stream) {
    const float* x = (const float*)d_in[0];   // [512, 2048] fp32
    const float* W = (const float*)d_in[1];   // [128, 10] fp32
    const float* b = (const float*)d_in[2];   // [128] fp32
    float* out = (float*)d_out;               // [512, 2048, 128] fp32
    int n = in_sizes[0];                      // 1,048,576 x-values

    // 2048 blocks = 8 per CU; each does n/(2048*32) = 16 grid-stride iters.
    bspline_enc_kernel<<<2048, 256, 0, stream>>>(x, W, b, out, n);
}